// Round 14
// baseline (1177.454 us; speedup 1.0000x reference)
//
#include <hip/hip_runtime.h>
#include <hip/hip_bf16.h>
#include <math.h>

#define D_MODEL 512
#define N_HEADS 8
#define D_HEAD  64
#define D_FF    2048
#define SEQ     512
#define BATCH   8
#define ROWS    (BATCH * SEQ)          /* 4096 */
#define PRED_LEN 96
#define KLEN_MASKED (SEQ - PRED_LEN)   /* 416 */
#define LN_EPS  1e-5f

typedef float  f32x4 __attribute__((ext_vector_type(4)));
typedef short  s16x8 __attribute__((ext_vector_type(8)));

__device__ __forceinline__ float bf2f(ushort u) {
    union { unsigned int i; float f; } c; c.i = ((unsigned int)u) << 16; return c.f;
}
__device__ __forceinline__ ushort f2bf(float v) {
    __hip_bfloat16 h = __float2bfloat16(v);
    return *(ushort*)&h;
}
__device__ __forceinline__ void gl_lds16(const void* g, void* lds) {
    __builtin_amdgcn_global_load_lds(
        (const __attribute__((address_space(1))) unsigned int*)g,
        (__attribute__((address_space(3))) unsigned int*)lds, 16, 0, 0);
}

/* XCD-aware chunked block swizzle (T1). Verified round 9: -120us. Bijective
 * when (gx*gy) % 8 == 0 -- true for every grid we launch; z untouched. */
__device__ __forceinline__ void swz8(int& x, int& y, int gx, int gy) {
    int n = gx * gy;
    int id = x + gx * y;
    int id2 = (id & 7) * (n >> 3) + (id >> 3);
    x = id2 % gx;
    y = id2 / gx;
}

/* ============ GEMM: LDS-staged, BK=64 (16 MFMAs per barrier) ===============
 * C = A[M,K] @ Bt[N,K]^T + bias (opt relu). BM=128, BN=64, BK=64, 4 waves 2x2.
 * __syncthreads double-buffer (verified): stage(t+1) -> compute(t) -> barrier.
 * LDS [row][64]; chunk p of row r holds logical k-chunk p ^ (r&7).
 * If VT != null, blocks with n0 >= vcol0 write transposed per-head V.
 */
struct GDesc {
    const ushort* A; int lda;
    const ushort* Bt; int ldb;
    ushort* C; int ldc;
    int N; int K;
    const float* bias; int relu;
    ushort* VT; int vcol0;
};

__device__ __forceinline__ void gemm_body(const GDesc& d, int bx, int by)
{
    __shared__ __attribute__((aligned(16))) ushort As[2][128 * 64];
    __shared__ __attribute__((aligned(16))) ushort Bs[2][64 * 64];
    const int tid = threadIdx.x;
    const int w = tid >> 6, lane = tid & 63;
    const int l16 = lane & 15, quad = lane >> 4;
    const int m0 = by * 128, n0 = bx * 64;
    const ushort* Ab = d.A + (size_t)m0 * d.lda;
    const ushort* Bb = d.Bt + (size_t)n0 * d.ldb;
    const int wm = (w >> 1) * 64, wn = (w & 1) * 32;
    const int nk = d.K >> 6;
    const int lr = lane >> 3, lc = lane & 7;
    const int ch = lc ^ lr;                     /* pre-swizzled source chunk */

    auto stage = [&](int buf, int k0) {
        #pragma unroll
        for (int q = 0; q < 4; ++q) {
            int seg = q * 4 + w;
            int row = seg * 8 + lr;
            gl_lds16(Ab + (size_t)row * d.lda + k0 + ch * 8,
                     (void*)(As[buf] + seg * 512));
        }
        #pragma unroll
        for (int q = 0; q < 2; ++q) {
            int seg = q * 4 + w;
            int row = seg * 8 + lr;
            gl_lds16(Bb + (size_t)row * d.ldb + k0 + ch * 8,
                     (void*)(Bs[buf] + seg * 512));
        }
    };

    f32x4 acc[4][2];
    #pragma unroll
    for (int i = 0; i < 4; ++i)
        #pragma unroll
        for (int j = 0; j < 2; ++j) acc[i][j] = (f32x4)0.f;

    auto compute = [&](int buf) {
        #pragma unroll
        for (int t2 = 0; t2 < 2; ++t2) {
            s16x8 af[4];
            #pragma unroll
            for (int i = 0; i < 4; ++i) {
                int r = wm + i * 16 + l16;
                int p = (t2 * 4 + quad) ^ (r & 7);
                af[i] = *(const s16x8*)(As[buf] + r * 64 + p * 8);
            }
            #pragma unroll
            for (int j = 0; j < 2; ++j) {
                int r = wn + j * 16 + l16;
                int p = (t2 * 4 + quad) ^ (r & 7);
                s16x8 bfr = *(const s16x8*)(Bs[buf] + r * 64 + p * 8);
                #pragma unroll
                for (int i = 0; i < 4; ++i)
                    acc[i][j] = __builtin_amdgcn_mfma_f32_16x16x32_bf16(af[i], bfr, acc[i][j], 0, 0, 0);
            }
        }
    };

    stage(0, 0);
    __syncthreads();
    int cur = 0;
    for (int t = 0; t < nk - 1; ++t) {
        stage(cur ^ 1, (t + 1) << 6);      /* issue next-tile loads FIRST */
        compute(cur);                       /* latency hides under this */
        __syncthreads();                    /* drains vmcnt -> buf^1 ready */
        cur ^= 1;
    }
    compute(cur);

    const bool isv = (d.VT != nullptr) && (n0 >= d.vcol0);
    if (isv) {
        #pragma unroll
        for (int i = 0; i < 4; ++i) {
            int mrow = m0 + wm + i * 16 + quad * 4;
            int b = mrow >> 9, pbase = mrow & 511;
            #pragma unroll
            for (int j = 0; j < 2; ++j) {
                int cv = n0 + wn + j * 16 + l16 - d.vcol0;   /* 0..511 */
                int h = cv >> 6, dd = cv & 63;
                union { ushort u[4]; uint2 v; } pk;
                #pragma unroll
                for (int r = 0; r < 4; ++r) pk.u[r] = f2bf(acc[i][j][r]);
                *(uint2*)(d.VT + ((size_t)((b * 8 + h) * 64 + dd) * 512 + pbase)) = pk.v;
            }
        }
    } else {
        #pragma unroll
        for (int i = 0; i < 4; ++i) {
            #pragma unroll
            for (int j = 0; j < 2; ++j) {
                int col = n0 + wn + j * 16 + l16;
                float bv = d.bias ? d.bias[col] : 0.f;
                #pragma unroll
                for (int r = 0; r < 4; ++r) {
                    float v = acc[i][j][r] + bv;
                    if (d.relu) v = fmaxf(v, 0.f);
                    d.C[(size_t)(m0 + wm + i * 16 + quad * 4 + r) * d.ldc + col] = f2bf(v);
                }
            }
        }
    }
}

__global__ __launch_bounds__(256) void gemm_one(GDesc d)
{
    int bx = blockIdx.x, by = blockIdx.y;
    swz8(bx, by, gridDim.x, gridDim.y);
    if (bx * 64 < d.N) gemm_body(d, bx, by);
}

__global__ __launch_bounds__(256) void gemm_two(GDesc d0, GDesc d1)
{
    const GDesc& d = blockIdx.z ? d1 : d0;
    int bx = blockIdx.x, by = blockIdx.y;
    swz8(bx, by, gridDim.x, gridDim.y);
    if (bx * 64 < d.N) gemm_body(d, bx, by);
}

/* ============ split-K GEMM for N=512 outputs (Wo-proj, FF2) =================
 * BK=64 body; z=2 K-slices (round-7: z=4 pays HBM bytes; round-10: atomic
 * finisher fusion crashed -> separate add_ln is the verified-safe form).
 */
struct SKDesc {
    const ushort* A; int lda;
    const ushort* Bt; int ldb;
    float* P;          /* [2][ROWS*512] */
    int K;             /* full K */
};

__global__ __launch_bounds__(256) void gemm_sk(SKDesc d)
{
    __shared__ __attribute__((aligned(16))) ushort As[2][128 * 64];
    __shared__ __attribute__((aligned(16))) ushort Bs[2][64 * 64];
    const int tid = threadIdx.x;
    const int w = tid >> 6, lane = tid & 63;
    const int l16 = lane & 15, quad = lane >> 4;
    int bx = blockIdx.x, by = blockIdx.y;
    swz8(bx, by, gridDim.x, gridDim.y);
    const int m0 = by * 128, n0 = bx * 64;
    const int slice = blockIdx.z;
    const int kb = slice * (d.K >> 1);
    const int nk = d.K >> 7;                 /* (K/2)/64 : 512->4, 2048->16 */
    const ushort* Ab = d.A + (size_t)m0 * d.lda + kb;
    const ushort* Bb = d.Bt + (size_t)n0 * d.ldb + kb;
    const int wm = (w >> 1) * 64, wn = (w & 1) * 32;
    const int lr = lane >> 3, lc = lane & 7;
    const int ch = lc ^ lr;

    auto stage = [&](int buf, int k0) {
        #pragma unroll
        for (int q = 0; q < 4; ++q) {
            int seg = q * 4 + w;
            int row = seg * 8 + lr;
            gl_lds16(Ab + (size_t)row * d.lda + k0 + ch * 8,
                     (void*)(As[buf] + seg * 512));
        }
        #pragma unroll
        for (int q = 0; q < 2; ++q) {
            int seg = q * 4 + w;
            int row = seg * 8 + lr;
            gl_lds16(Bb + (size_t)row * d.ldb + k0 + ch * 8,
                     (void*)(Bs[buf] + seg * 512));
        }
    };

    f32x4 acc[4][2];
    #pragma unroll
    for (int i = 0; i < 4; ++i)
        #pragma unroll
        for (int j = 0; j < 2; ++j) acc[i][j] = (f32x4)0.f;

    auto compute = [&](int buf) {
        #pragma unroll
        for (int t2 = 0; t2 < 2; ++t2) {
            s16x8 af[4];
            #pragma unroll
            for (int i = 0; i < 4; ++i) {
                int r = wm + i * 16 + l16;
                int p = (t2 * 4 + quad) ^ (r & 7);
                af[i] = *(const s16x8*)(As[buf] + r * 64 + p * 8);
            }
            #pragma unroll
            for (int j = 0; j < 2; ++j) {
                int r = wn + j * 16 + l16;
                int p = (t2 * 4 + quad) ^ (r & 7);
                s16x8 bfr = *(const s16x8*)(Bs[buf] + r * 64 + p * 8);
                #pragma unroll
                for (int i = 0; i < 4; ++i)
                    acc[i][j] = __builtin_amdgcn_mfma_f32_16x16x32_bf16(af[i], bfr, acc[i][j], 0, 0, 0);
            }
        }
    };

    stage(0, 0);
    __syncthreads();
    int cur = 0;
    for (int t = 0; t < nk - 1; ++t) {
        stage(cur ^ 1, (t + 1) << 6);
        compute(cur);
        __syncthreads();
        cur ^= 1;
    }
    compute(cur);

    float* P = d.P + (size_t)slice * ((size_t)ROWS * 512);
    #pragma unroll
    for (int i = 0; i < 4; ++i) {
        #pragma unroll
        for (int j = 0; j < 2; ++j) {
            int col = n0 + wn + j * 16 + l16;
            #pragma unroll
            for (int r = 0; r < 4; ++r)
                P[(size_t)(m0 + wm + i * 16 + quad * 4 + r) * 512 + col] = acc[i][j][r];
        }
    }
}

/* ============ flash attention: O = softmax(Q K^T / 8, klen) V ===============
 * QBLK=32, 128-thread blocks (2 waves), grid (16,64) = 1024 blocks = 4
 * blocks/CU; independent blocks overlap softmax with MFMA (verified rd 13).
 * Masked QK skip; K0/V0 prefetch hoists; XCD swizzle.
 */
__global__ __launch_bounds__(128) void flash_attn(
    const ushort* __restrict__ Q, int ldq,
    const ushort* __restrict__ K, int ldk,
    const ushort* __restrict__ Vt,
    ushort* __restrict__ O, int ldo, int klen)
{
    __shared__ __attribute__((aligned(16))) ushort KVs[8192];
    __shared__ __attribute__((aligned(16))) ushort Es[2][2048];
    const int tid = threadIdx.x, w = tid >> 6, lane = tid & 63;
    const int l16 = lane & 15, quad = lane >> 4;
    int bqx = blockIdx.x, bhy = blockIdx.y;
    swz8(bqx, bhy, gridDim.x, gridDim.y);
    const int bh = bhy, b = bh >> 3, h = bh & 7;
    const int q0 = bqx * 32;

    const ushort* Qb = Q + (size_t)(b * SEQ) * ldq + h * D_HEAD;
    const ushort* Kb = K + (size_t)(b * SEQ) * ldk + h * D_HEAD;
    const ushort* Vb = Vt + (size_t)bh * (D_HEAD * SEQ);

    auto stageK = [&](int kc) {
        #pragma unroll
        for (int it = 0; it < 8; ++it) {
            int cc = (it * 2 + w) * 64 + lane;
            int row = cc >> 3;
            int dch = (cc & 7) ^ (row & 7);
            gl_lds16(Kb + (size_t)(kc * 128 + row) * ldk + dch * 8,
                     (void*)(KVs + (size_t)(it * 2 + w) * 512));
        }
    };
    auto stageV = [&](int kc) {
        #pragma unroll
        for (int it = 0; it < 8; ++it) {
            int cc = (it * 2 + w) * 64 + lane;
            int dd = cc >> 4;
            int kch = (cc & 15) ^ (dd & 15);
            gl_lds16(Vb + (size_t)dd * SEQ + kc * 128 + kch * 8,
                     (void*)(KVs + (size_t)(it * 2 + w) * 512));
        }
    };

    stageK(0);                           /* K0 latency hides under Q loads */

    s16x8 af0, af1;
    {
        const ushort* qr = Qb + (size_t)(q0 + w * 16 + l16) * ldq + quad * 8;
        af0 = *(const s16x8*)(qr);
        af1 = *(const s16x8*)(qr + 32);
    }

    f32x4 sc[32];

    #pragma unroll
    for (int kc = 0; kc < 4; ++kc) {
        if (kc > 0) stageK(kc);          /* after prev trailing barrier: safe */
        __syncthreads();                 /* K(kc) staged */
        #pragma unroll
        for (int kt = 0; kt < 8; ++kt) {
            if (kc * 128 + kt * 16 < klen) {   /* skip fully-masked key tiles */
                int r0 = kt * 16 + l16;
                s16x8 b0 = *(const s16x8*)(KVs + r0 * 64 + ((quad)     ^ (r0 & 7)) * 8);
                s16x8 b1 = *(const s16x8*)(KVs + r0 * 64 + ((4 + quad) ^ (r0 & 7)) * 8);
                f32x4 a = __builtin_amdgcn_mfma_f32_16x16x32_bf16(af0, b0, (f32x4)0.f, 0, 0, 0);
                sc[kc * 8 + kt] = __builtin_amdgcn_mfma_f32_16x16x32_bf16(af1, b1, a, 0, 0, 0);
            }
        }
        __syncthreads();                 /* all waves done reading KVs */
    }

    stageV(0);                           /* V0 latency hides under softmax */

    float inv[4];
    #pragma unroll
    for (int r = 0; r < 4; ++r) {
        float m = -1e30f;
        #pragma unroll
        for (int j = 0; j < 32; ++j) {
            bool valid = (j * 16 + l16) < klen;
            m = valid ? fmaxf(m, sc[j][r]) : m;
        }
        m = fmaxf(m, __shfl_xor(m, 1));
        m = fmaxf(m, __shfl_xor(m, 2));
        m = fmaxf(m, __shfl_xor(m, 4));
        m = fmaxf(m, __shfl_xor(m, 8));
        float ssum = 0.f;
        #pragma unroll
        for (int j = 0; j < 32; ++j) {
            bool valid = (j * 16 + l16) < klen;
            float e = valid ? __expf((sc[j][r] - m) * 0.125f) : 0.f;
            sc[j][r] = e;                /* unconditional: zeroes masked tiles */
            ssum += e;
        }
        ssum += __shfl_xor(ssum, 1);
        ssum += __shfl_xor(ssum, 2);
        ssum += __shfl_xor(ssum, 4);
        ssum += __shfl_xor(ssum, 8);
        inv[r] = 1.f / ssum;
    }

    f32x4 oacc[4];
    #pragma unroll
    for (int jd = 0; jd < 4; ++jd) oacc[jd] = (f32x4)0.f;
    #pragma unroll
    for (int kc = 0; kc < 4; ++kc) {
        if (kc > 0) stageV(kc);          /* after prev trailing barrier: safe */
        #pragma unroll
        for (int j = 0; j < 8; ++j) {
            int lcj = j * 2 + (l16 >> 3);
            #pragma unroll
            for (int r = 0; r < 4; ++r) {
                int m = quad * 4 + r;
                Es[w][m * 128 + (lcj ^ m) * 8 + (l16 & 7)] = f2bf(sc[kc * 8 + j][r]);
            }
        }
        __syncthreads();                 /* V(kc) staged (vmcnt drained) */
        #pragma unroll
        for (int ks = 0; ks < 4; ++ks) {
            int lc = ks * 4 + quad;
            s16x8 ea = *(const s16x8*)(&Es[w][l16 * 128 + (lc ^ l16) * 8]);
            #pragma unroll
            for (int jd = 0; jd < 4; ++jd) {
                int row = jd * 16 + l16;
                s16x8 vb = *(const s16x8*)(KVs + row * 128 + (lc ^ l16) * 8);
                oacc[jd] = __builtin_amdgcn_mfma_f32_16x16x32_bf16(ea, vb, oacc[jd], 0, 0, 0);
            }
        }
        __syncthreads();                 /* all waves done reading KVs/Es */
    }

    ushort* Ob = O + (size_t)(b * SEQ) * ldo + h * D_HEAD;
    #pragma unroll
    for (int jd = 0; jd < 4; ++jd)
        #pragma unroll
        for (int r = 0; r < 4; ++r)
            Ob[(size_t)(q0 + w * 16 + quad * 4 + r) * ldo + jd * 16 + l16] =
                f2bf(oacc[jd][r] * inv[r]);
}

/* ============ merged weight repack: 64x64 tiles, full coalescing ============
 * Round-14: old 32x32 tiles ran at 2.4 TB/s (64B write granules). 64x64:
 * reads 256B-contiguous per 16 lanes (f32x4 each), LDS [64][65] (pad ->
 * column reads conflict-free; 8-thread groups alias banks 2-way = free),
 * writes 128B-contiguous per 8 lanes (s16x8 each, 2 passes).
 */
struct AttnPtrs { const float* p[48]; };
struct FfPtrs   { const float* p[16]; };

__global__ __launch_bounds__(256) void repack_all(
    AttnPtrs A, FfPtrs F, ushort* __restrict__ wa, ushort* __restrict__ wf)
{
    __shared__ float t[64][65];
    const int tid = threadIdx.x;
    const int id = blockIdx.x;
    const float* in; ushort* o; int Kd, Nd, n0, k0;
    if (id < 3072) {                     /* attn: 48 mats x 64 tiles (8x8) */
        int z = id >> 6, tt = id & 63;
        Kd = 512; Nd = 512;
        n0 = (tt & 7) * 64; k0 = (tt >> 3) * 64;
        in = A.p[z];
        o = wa + (size_t)z * 262144;
    } else {                             /* ff: 16 mats x 256 tiles */
        int id2 = id - 3072;
        int z = id2 >> 8, tt = id2 & 255;
        Kd = (z < 8) ? 512 : 2048; Nd = (z < 8) ? 2048 : 512;
        int tn = Nd / 64;
        n0 = (tt % tn) * 64; k0 = (tt / tn) * 64;
        in = F.p[z];
        o = wf + (size_t)z * (512 * 2048);
    }
    {   /* read 64x64 f32 tile: f32x4 per thread x 4 rows */
        int kr = tid >> 4;               /* 0..15 */
        int c4 = (tid & 15) * 4;         /* 0..60 */
        #pragma unroll
        for (int r = 0; r < 4; ++r) {
            int k = kr + r * 16;
            f32x4 v = *(const f32x4*)(in + (size_t)(k0 + k) * Nd + n0 + c4);
            t[k][c4] = v[0]; t[k][c4 + 1] = v[1];
            t[k][c4 + 2] = v[2]; t[k][c4 + 3] = v[3];
        }
    }
    __syncthreads();
    {   /* write transposed bf16: 16B per thread, 2 passes of 32 rows */
        int kb = (tid & 7) * 8;          /* 0..56 */
        int nr = tid >> 3;               /* 0..31 */
        #pragma unroll
        for (int pass = 0; pass < 2; ++pass) {
            int n = nr + pass * 32;
            union { ushort u[8]; s16x8 w8; } pk;
            #pragma unroll
            for (int j = 0; j < 8; ++j)
                pk.u[j] = f2bf(t[kb + j][n]);
            *(s16x8*)(o + (size_t)(n0 + n) * Kd + k0 + kb) = pk.w8;
        }
    }
}

/* ============ dual input projection (z=0 src, z=1 tgt) ============ */
__global__ __launch_bounds__(256) void input_proj2(
    const float* __restrict__ x0, const float* __restrict__ w0,
    const float* __restrict__ b0, const float* __restrict__ p0,
    float* __restrict__ o0_32, ushort* __restrict__ o0_b, int in0,
    const float* __restrict__ x1, const float* __restrict__ w1,
    const float* __restrict__ b1, const float* __restrict__ p1,
    float* __restrict__ o1_32, ushort* __restrict__ o1_b, int in1)
{
    const int z = blockIdx.y;
    const float* x = z ? x1 : x0;  const float* w = z ? w1 : w0;
    const float* bias = z ? b1 : b0; const float* pos = z ? p1 : p0;
    float* out32 = z ? o1_32 : o0_32; ushort* outb = z ? o1_b : o0_b;
    int in_size = z ? in1 : in0;
    int idx = blockIdx.x * 256 + threadIdx.x;
    int col = idx & (D_MODEL - 1);
    int row = idx >> 9;
    int l   = row & (SEQ - 1);
    const float* xr = x + (size_t)row * in_size;
    float acc = bias[col] + pos[(size_t)l * D_MODEL + col];
    for (int t = 0; t < in_size; ++t) acc += xr[t] * w[(size_t)t * D_MODEL + col];
    out32[idx] = acc;
    outb[idx]  = f2bf(acc);
}

/* ============ split-K reduce + opt gemm-bias + residual + LayerNorm ========
 * one 64-lane wave per 512-col row. p = f32 partials [2][ROWS*512].
 */
__global__ __launch_bounds__(256) void add_ln2(
    const float* __restrict__ p, const float* __restrict__ gb,
    const float* __restrict__ x,
    const float* __restrict__ g, const float* __restrict__ b,
    float* __restrict__ out32, ushort* __restrict__ outb)
{
    const int row  = blockIdx.x * 4 + (threadIdx.x >> 6);
    const int lane = threadIdx.x & 63;
    const int c0   = lane * 8;
    const size_t base = (size_t)row * D_MODEL + c0;
    const float* p1 = p + (size_t)ROWS * 512;
    f32x4 a0 = *(const f32x4*)(p + base),  a1 = *(const f32x4*)(p + base + 4);
    f32x4 c0v= *(const f32x4*)(p1 + base), c1v= *(const f32x4*)(p1 + base + 4);
    f32x4 x0 = *(const f32x4*)(x + base),  x1 = *(const f32x4*)(x + base + 4);
    float v[8];
    #pragma unroll
    for (int j = 0; j < 4; ++j) {
        v[j]     = a0[j] + c0v[j] + x0[j];
        v[4 + j] = a1[j] + c1v[j] + x1[j];
    }
    if (gb) {
        f32x4 gb0 = *(const f32x4*)(gb + c0), gb1 = *(const f32x4*)(gb + c0 + 4);
        #pragma unroll
        for (int j = 0; j < 4; ++j) { v[j] += gb0[j]; v[4 + j] += gb1[j]; }
    }
    float s = 0.f;
    #pragma unroll
    for (int j = 0; j < 8; ++j) s += v[j];
    #pragma unroll
    for (int off = 32; off; off >>= 1) s += __shfl_xor(s, off);
    float mu = s * (1.f / D_MODEL);
    float q = 0.f;
    #pragma unroll
    for (int j = 0; j < 8; ++j) { v[j] -= mu; q += v[j] * v[j]; }
    #pragma unroll
    for (int off = 32; off; off >>= 1) q += __shfl_xor(q, off);
    float rs = rsqrtf(q * (1.f / D_MODEL) + LN_EPS);
    f32x4 g0 = *(const f32x4*)(g + c0), g1 = *(const f32x4*)(g + c0 + 4);
    f32x4 b0 = *(const f32x4*)(b + c0), b1 = *(const f32x4*)(b + c0 + 4);
    f32x4 y0, y1;
    union { ushort u[8]; s16x8 w; } pk;
    #pragma unroll
    for (int j = 0; j < 4; ++j) {
        y0[j] = v[j]     * rs * g0[j] + b0[j];
        y1[j] = v[4 + j] * rs * g1[j] + b1[j];
        pk.u[j]     = f2bf(y0[j]);
        pk.u[4 + j] = f2bf(y1[j]);
    }
    *(f32x4*)(out32 + base)     = y0;
    *(f32x4*)(out32 + base + 4) = y1;
    *(s16x8*)(outb + base)      = pk.w;
}

/* ============ final projection: one wave per row, contiguous W reads ======= */
__global__ __launch_bounds__(256) void final_proj(
    const float* __restrict__ X, const float* __restrict__ W,
    const float* __restrict__ b, float* __restrict__ out)
{
    const int row  = blockIdx.x * 4 + (threadIdx.x >> 6);
    const int lane = threadIdx.x & 63;
    const float* xr = X + (size_t)row * D_MODEL + lane * 8;
    f32x4 x0 = *(const f32x4*)(xr), x1 = *(const f32x4*)(xr + 4);
    const float* wr = W + (size_t)lane * 64;      /* rows lane*8..lane*8+7, 8 cols */
    f32x4 pa = (f32x4)0.f, pb = (f32x4)0.f;
    #pragma unroll
    for (int j = 0; j < 8; ++j) {
        float xv = (j < 4) ? x0[j] : x1[j - 4];
        f32x4 w0 = *(const f32x4*)(wr + j * 8);
        f32x4 w1 = *(const f32x4*)(wr + j * 8 + 4);
        #pragma unroll
        for (int c = 0; c < 4; ++c) { pa[c] += xv * w0[c]; pb[c] += xv * w1[c]; }
    }
    #pragma unroll
    for (int off = 32; off; off >>= 1) {
        #pragma unroll
        for (int c = 0; c < 4; ++c) {
            pa[c] += __shfl_xor(pa[c], off);
            pb[c] += __shfl_xor(pb[c], off);
        }
    }
    if (lane == 0) {
        float* o = out + (size_t)row * 8;
        #pragma unroll
        for (int c = 0; c < 4; ++c) { o[c] = pa[c] + b[c]; o[4 + c] = pb[c] + b[4 + c]; }
    }
}

/* ============================ host orchestration ============================ */
extern "C" void kernel_launch(void* const* d_in, const int* in_sizes, int n_in,
                              void* d_out, int out_size, void* d_ws, size_t ws_size,
                              hipStream_t stream)
{
    const float* src         = (const float*)d_in[0];
    const float* tgt         = (const float*)d_in[1];
    const float* src_pos     = (const float*)d_in[2];
    const float* tgt_pos     = (const float*)d_in[3];
    const float* src_lin_w   = (const float*)d_in[4];
    const float* src_lin_b   = (const float*)d_in[5];
    const float* tgt_lin_w   = (const float*)d_in[6];
    const float* tgt_lin_b   = (const float*)d_in[7];
    const float* enc_wq      = (const float*)d_in[8];
    const float* enc_wk      = (const float*)d_in[9];
    const float* enc_wv      = (const float*)d_in[10];
    const float* enc_wo      = (const float*)d_in[11];
    const float* enc_ff1_w   = (const float*)d_in[12];
    const float* enc_ff1_b   = (const float*)d_in[13];
    const float* enc_ff2_w   = (const float*)d_in[14];
    const float* enc_ff2_b   = (const float*)d_in[15];
    const float* enc_ln1_g   = (const float*)d_in[16];
    const float* enc_ln1_b   = (const float*)d_in[17];
    const float* enc_ln2_g   = (const float*)d_in[18];
    const float* enc_ln2_b   = (const float*)d_in[19];
    const float* dec_sa_wq   = (const float*)d_in[20];
    const float* dec_sa_wk   = (const float*)d_in[21];
    const float* dec_sa_wv   = (const float*)d_in[22];
    const float* dec_sa_wo   = (const float*)d_in[23];
    const float* dec_ca_wq   = (const float*)d_in[24];
    const float* dec_ca_wk   = (const float*)d_in[25];
    const float* dec_ca_wv   = (const float*)d_in[26];
    const float* dec_ca_wo   = (const float*)d_in[27];
    const float* dec_ff1_w   = (const float*)d_in[28];
    const float* dec_ff1_b   = (const float*)d_in[29];
    const float* dec_ff2_w   = (const float*)d_in[30];
    const float* dec_ff2_b   = (const float*)d_in[31];
    const float* dec_ln1_g   = (const float*)d_in[32];
    const float* dec_ln1_b   = (const float*)d_in[33];
    const float* dec_ln2_g   = (const float*)d_in[34];
    const float* dec_ln2_b   = (const float*)d_in[35];
    const float* dec_ln3_g   = (const float*)d_in[36];
    const float* dec_ln3_b   = (const float*)d_in[37];
    const float* proj_w      = (const float*)d_in[38];
    const float* proj_b      = (const float*)d_in[39];

    /* ---- workspace carve ---- */
    char* p = (char*)d_ws;
    auto carve = [&](size_t bytes) { char* r = p; p += (bytes + 255) & ~(size_t)255; return r; };
    ushort* enc_xb = (ushort*)carve((size_t)ROWS * D_MODEL * 2);
    ushort* dec_xb = (ushort*)carve((size_t)ROWS * D_MODEL * 2);
    float*  enc_x32= (float*) carve((size_t)ROWS * D_MODEL * 4);
    float*  dec_x32= (float*) carve((size_t)ROWS * D_MODEL * 4);
    ushort* qkvb   = (ushort*)carve((size_t)ROWS * 1536 * 2);
    ushort* qb     = (ushort*)carve((size_t)ROWS * D_MODEL * 2);
    ushort* kvb    = (ushort*)carve((size_t)ROWS * 1024 * 2);
    ushort* ctxb   = (ushort*)carve((size_t)ROWS * D_MODEL * 2);
    float*  pf     = (float*) carve((size_t)2 * ROWS * D_MODEL * 4);
    ushort* ffhb   = (ushort*)carve((size_t)ROWS * D_FF * 2);
    ushort* vt     = (ushort*)carve((size_t)64 * D_HEAD * SEQ * 2);
    ushort* wa     = (ushort*)carve((size_t)48 * 262144 * 2);
    ushort* wf     = (ushort*)carve((size_t)16 * 1048576 * 2);

    const dim3 blk(256);

    /* ---- weight repack (1 merged launch, 64x64 tiles) ---- */
    {
        AttnPtrs A;
        for (int i = 0; i < 4; ++i) {
            const size_t o = (size_t)i * 262144;
            A.p[i * 3 + 0] = enc_wq + o;  A.p[i * 3 + 1] = enc_wk + o;  A.p[i * 3 + 2] = enc_wv + o;
            A.p[12 + i] = enc_wo + o;
            A.p[16 + i * 3 + 0] = dec_sa_wq + o; A.p[16 + i * 3 + 1] = dec_sa_wk + o;
            A.p[16 + i * 3 + 2] = dec_sa_wv + o;
            A.p[28 + i] = dec_sa_wo + o;
            A.p[32 + i * 2 + 0] = dec_ca_wk + o; A.p[32 + i * 2 + 1] = dec_ca_wv + o;
            A.p[40 + i] = dec_ca_wq + o;
            A.p[44 + i] = dec_ca_wo + o;
        }
        FfPtrs F;
        for (int i = 0; i < 4; ++i) {
            F.p[0 + i]  = enc_ff1_w + (size_t)i * 1048576;
            F.p[4 + i]  = dec_ff1_w + (size_t)i * 1048576;
            F.p[8 + i]  = enc_ff2_w + (size_t)i * 1048576;
            F.p[12 + i] = dec_ff2_w + (size_t)i * 1048576;
        }
        repack_all<<<dim3(3072 + 4096), blk, 0, stream>>>(A, F, wa, wf);
    }

    auto mkd = [&](const ushort* A, int lda, const ushort* Bt, int ldb,
                   ushort* C, int ldc, int N, int K,
                   const float* bias, int relu, ushort* VT, int vcol0) {
        GDesc d; d.A = A; d.lda = lda; d.Bt = Bt; d.ldb = ldb;
        d.C = C; d.ldc = ldc; d.N = N; d.K = K;
        d.bias = bias; d.relu = relu; d.VT = VT; d.vcol0 = vcol0;
        return d;
    };
    auto g64 = [&](const GDesc& d) {
        gemm_one<<<dim3(d.N / 64, ROWS / 128), blk, 0, stream>>>(d);
    };
    auto gsk = [&](const ushort* A, int lda, const ushort* Bt, int K) {
        SKDesc d; d.A = A; d.lda = lda; d.Bt = Bt; d.ldb = K; d.P = pf; d.K = K;
        gemm_sk<<<dim3(8, ROWS / 128, 2), blk, 0, stream>>>(d);
    };

    /* input projections (1 launch) */
    input_proj2<<<dim3(ROWS * D_MODEL / 256, 2), blk, 0, stream>>>(
        src, src_lin_w, src_lin_b, src_pos, enc_x32, enc_xb, 16,
        tgt, tgt_lin_w, tgt_lin_b, tgt_pos, dec_x32, dec_xb, 8);

    /* ===================== encoder ===================== */
    for (int i = 0; i < 4; ++i) {
        g64(mkd(enc_xb, 512, wa + (size_t)(i * 3) * 262144, 512, qkvb, 1536,
                1536, 512, nullptr, 0, vt, 1024));
        flash_attn<<<dim3(16, 64), dim3(128), 0, stream>>>(qkvb, 1536, qkvb + 512, 1536, vt,
                                                           ctxb, D_MODEL, SEQ);
        gsk(ctxb, 512, wa + (size_t)(12 + i) * 262144, 512);
        add_ln2<<<ROWS / 4, blk, 0, stream>>>(pf, nullptr, enc_x32,
                                              enc_ln1_g + i * 512, enc_ln1_b + i * 512,
                                              enc_x32, enc_xb);
        g64(mkd(enc_xb, 512, wf + (size_t)i * 1048576, 512, ffhb, 2048,
                2048, 512, enc_ff1_b + i * 2048, 1, nullptr, 0));
        gsk(ffhb, 2048, wf + (size_t)(8 + i) * 1048576, 2048);
        add_ln2<<<ROWS / 4, blk, 0, stream>>>(pf, enc_ff2_b + i * 512, enc_x32,
                                              enc_ln2_g + i * 512, enc_ln2_b + i * 512,
                                              enc_x32, enc_xb);
    }

    /* ===================== decoder ===================== */
    for (int i = 0; i < 4; ++i) {
        /* masked self-attention */
        g64(mkd(dec_xb, 512, wa + (size_t)(16 + i * 3) * 262144, 512, qkvb, 1536,
                1536, 512, nullptr, 0, vt, 1024));
        flash_attn<<<dim3(16, 64), dim3(128), 0, stream>>>(qkvb, 1536, qkvb + 512, 1536, vt,
                                                           ctxb, D_MODEL, KLEN_MASKED);
        gsk(ctxb, 512, wa + (size_t)(28 + i) * 262144, 512);
        add_ln2<<<ROWS / 4, blk, 0, stream>>>(pf, nullptr, dec_x32,
                                              dec_ln1_g + i * 512, dec_ln1_b + i * 512,
                                              dec_x32, dec_xb);
        /* cross-attention: q-proj (dec_x) and kv-proj (enc_x) in ONE launch */
        {
            GDesc dq = mkd(dec_xb, 512, wa + (size_t)(40 + i) * 262144, 512, qb, 512,
                           512, 512, nullptr, 0, nullptr, 0);
            GDesc dkv = mkd(enc_xb, 512, wa + (size_t)(32 + i * 2) * 262144, 512, kvb, 1024,
                            1024, 512, nullptr, 0, vt, 512);
            gemm_two<<<dim3(16, ROWS / 128, 2), blk, 0, stream>>>(dq, dkv);
        }
        flash_attn<<<dim3(16, 64), dim3(128), 0, stream>>>(qb, 512, kvb, 1024, vt,
                                                           ctxb, D_MODEL, SEQ);
        gsk(ctxb, 512, wa + (size_t)(44 + i) * 262144, 512);
        add_ln2<<<ROWS / 4, blk, 0, stream>>>(pf, nullptr, dec_x32,
                                              dec_ln2_g + i * 512, dec_ln2_b + i * 512,
                                              dec_x32, dec_xb);
        /* feed-forward */
        g64(mkd(dec_xb, 512, wf + (size_t)(4 + i) * 1048576, 512, ffhb, 2048,
                2048, 512, dec_ff1_b + i * 2048, 1, nullptr, 0));
        gsk(ffhb, 2048, wf + (size_t)(12 + i) * 1048576, 2048);
        add_ln2<<<ROWS / 4, blk, 0, stream>>>(pf, dec_ff2_b + i * 512, dec_x32,
                                              dec_ln3_g + i * 512, dec_ln3_b + i * 512,
                                              dec_x32, dec_xb);
    }

    /* final projection */
    final_proj<<<ROWS / 4, blk, 0, stream>>>(dec_x32, proj_w, proj_b, (float*)d_out);
}

// Round 15
// 1142.781 us; speedup vs baseline: 1.0303x; 1.0303x over previous
//
#include <hip/hip_runtime.h>
#include <hip/hip_bf16.h>
#include <math.h>

#define D_MODEL 512
#define N_HEADS 8
#define D_HEAD  64
#define D_FF    2048
#define SEQ     512
#define BATCH   8
#define ROWS    (BATCH * SEQ)          /* 4096 */
#define PRED_LEN 96
#define KLEN_MASKED (SEQ - PRED_LEN)   /* 416 */
#define LN_EPS  1e-5f

typedef float  f32x4 __attribute__((ext_vector_type(4)));
typedef short  s16x8 __attribute__((ext_vector_type(8)));

__device__ __forceinline__ float bf2f(ushort u) {
    union { unsigned int i; float f; } c; c.i = ((unsigned int)u) << 16; return c.f;
}
__device__ __forceinline__ ushort f2bf(float v) {
    __hip_bfloat16 h = __float2bfloat16(v);
    return *(ushort*)&h;
}
__device__ __forceinline__ void gl_lds16(const void* g, void* lds) {
    __builtin_amdgcn_global_load_lds(
        (const __attribute__((address_space(1))) unsigned int*)g,
        (__attribute__((address_space(3))) unsigned int*)lds, 16, 0, 0);
}

/* XCD-aware chunked block swizzle (T1). Verified round 9: -120us. Bijective
 * when (gx*gy) % 8 == 0 -- true for every grid we launch; z untouched. */
__device__ __forceinline__ void swz8(int& x, int& y, int gx, int gy) {
    int n = gx * gy;
    int id = x + gx * y;
    int id2 = (id & 7) * (n >> 3) + (id >> 3);
    x = id2 % gx;
    y = id2 / gx;
}

/* ============ GEMM: LDS-staged, BK=64 (16 MFMAs per barrier) ===============
 * C = A[M,K] @ Bt[N,K]^T + bias (opt relu). BM=128, BN=64, BK=64, 4 waves 2x2.
 * __syncthreads double-buffer (verified): stage(t+1) -> compute(t) -> barrier.
 * LDS [row][64]; chunk p of row r holds logical k-chunk p ^ (r&7).
 * If VT != null, blocks with n0 >= vcol0 write transposed per-head V.
 */
struct GDesc {
    const ushort* A; int lda;
    const ushort* Bt; int ldb;
    ushort* C; int ldc;
    int N; int K;
    const float* bias; int relu;
    ushort* VT; int vcol0;
};

__device__ __forceinline__ void gemm_body(const GDesc& d, int bx, int by)
{
    __shared__ __attribute__((aligned(16))) ushort As[2][128 * 64];
    __shared__ __attribute__((aligned(16))) ushort Bs[2][64 * 64];
    const int tid = threadIdx.x;
    const int w = tid >> 6, lane = tid & 63;
    const int l16 = lane & 15, quad = lane >> 4;
    const int m0 = by * 128, n0 = bx * 64;
    const ushort* Ab = d.A + (size_t)m0 * d.lda;
    const ushort* Bb = d.Bt + (size_t)n0 * d.ldb;
    const int wm = (w >> 1) * 64, wn = (w & 1) * 32;
    const int nk = d.K >> 6;
    const int lr = lane >> 3, lc = lane & 7;
    const int ch = lc ^ lr;                     /* pre-swizzled source chunk */

    auto stage = [&](int buf, int k0) {
        #pragma unroll
        for (int q = 0; q < 4; ++q) {
            int seg = q * 4 + w;
            int row = seg * 8 + lr;
            gl_lds16(Ab + (size_t)row * d.lda + k0 + ch * 8,
                     (void*)(As[buf] + seg * 512));
        }
        #pragma unroll
        for (int q = 0; q < 2; ++q) {
            int seg = q * 4 + w;
            int row = seg * 8 + lr;
            gl_lds16(Bb + (size_t)row * d.ldb + k0 + ch * 8,
                     (void*)(Bs[buf] + seg * 512));
        }
    };

    f32x4 acc[4][2];
    #pragma unroll
    for (int i = 0; i < 4; ++i)
        #pragma unroll
        for (int j = 0; j < 2; ++j) acc[i][j] = (f32x4)0.f;

    auto compute = [&](int buf) {
        #pragma unroll
        for (int t2 = 0; t2 < 2; ++t2) {
            s16x8 af[4];
            #pragma unroll
            for (int i = 0; i < 4; ++i) {
                int r = wm + i * 16 + l16;
                int p = (t2 * 4 + quad) ^ (r & 7);
                af[i] = *(const s16x8*)(As[buf] + r * 64 + p * 8);
            }
            #pragma unroll
            for (int j = 0; j < 2; ++j) {
                int r = wn + j * 16 + l16;
                int p = (t2 * 4 + quad) ^ (r & 7);
                s16x8 bfr = *(const s16x8*)(Bs[buf] + r * 64 + p * 8);
                #pragma unroll
                for (int i = 0; i < 4; ++i)
                    acc[i][j] = __builtin_amdgcn_mfma_f32_16x16x32_bf16(af[i], bfr, acc[i][j], 0, 0, 0);
            }
        }
    };

    stage(0, 0);
    __syncthreads();
    int cur = 0;
    for (int t = 0; t < nk - 1; ++t) {
        stage(cur ^ 1, (t + 1) << 6);      /* issue next-tile loads FIRST */
        compute(cur);                       /* latency hides under this */
        __syncthreads();                    /* drains vmcnt -> buf^1 ready */
        cur ^= 1;
    }
    compute(cur);

    const bool isv = (d.VT != nullptr) && (n0 >= d.vcol0);
    if (isv) {
        #pragma unroll
        for (int i = 0; i < 4; ++i) {
            int mrow = m0 + wm + i * 16 + quad * 4;
            int b = mrow >> 9, pbase = mrow & 511;
            #pragma unroll
            for (int j = 0; j < 2; ++j) {
                int cv = n0 + wn + j * 16 + l16 - d.vcol0;   /* 0..511 */
                int h = cv >> 6, dd = cv & 63;
                union { ushort u[4]; uint2 v; } pk;
                #pragma unroll
                for (int r = 0; r < 4; ++r) pk.u[r] = f2bf(acc[i][j][r]);
                *(uint2*)(d.VT + ((size_t)((b * 8 + h) * 64 + dd) * 512 + pbase)) = pk.v;
            }
        }
    } else {
        #pragma unroll
        for (int i = 0; i < 4; ++i) {
            #pragma unroll
            for (int j = 0; j < 2; ++j) {
                int col = n0 + wn + j * 16 + l16;
                float bv = d.bias ? d.bias[col] : 0.f;
                #pragma unroll
                for (int r = 0; r < 4; ++r) {
                    float v = acc[i][j][r] + bv;
                    if (d.relu) v = fmaxf(v, 0.f);
                    d.C[(size_t)(m0 + wm + i * 16 + quad * 4 + r) * d.ldc + col] = f2bf(v);
                }
            }
        }
    }
}

__global__ __launch_bounds__(256) void gemm_one(GDesc d)
{
    int bx = blockIdx.x, by = blockIdx.y;
    swz8(bx, by, gridDim.x, gridDim.y);
    if (bx * 64 < d.N) gemm_body(d, bx, by);
}

__global__ __launch_bounds__(256) void gemm_two(GDesc d0, GDesc d1)
{
    const GDesc& d = blockIdx.z ? d1 : d0;
    int bx = blockIdx.x, by = blockIdx.y;
    swz8(bx, by, gridDim.x, gridDim.y);
    if (bx * 64 < d.N) gemm_body(d, bx, by);
}

/* ============ split-K GEMM for N=512 outputs (Wo-proj, FF2) =================
 * BK=64 body; z=2 K-slices (round-7: z=4 pays HBM bytes; round-10: atomic
 * finisher fusion crashed -> separate add_ln is the verified-safe form).
 */
struct SKDesc {
    const ushort* A; int lda;
    const ushort* Bt; int ldb;
    float* P;          /* [2][ROWS*512] */
    int K;             /* full K */
};

__global__ __launch_bounds__(256) void gemm_sk(SKDesc d)
{
    __shared__ __attribute__((aligned(16))) ushort As[2][128 * 64];
    __shared__ __attribute__((aligned(16))) ushort Bs[2][64 * 64];
    const int tid = threadIdx.x;
    const int w = tid >> 6, lane = tid & 63;
    const int l16 = lane & 15, quad = lane >> 4;
    int bx = blockIdx.x, by = blockIdx.y;
    swz8(bx, by, gridDim.x, gridDim.y);
    const int m0 = by * 128, n0 = bx * 64;
    const int slice = blockIdx.z;
    const int kb = slice * (d.K >> 1);
    const int nk = d.K >> 7;                 /* (K/2)/64 : 512->4, 2048->16 */
    const ushort* Ab = d.A + (size_t)m0 * d.lda + kb;
    const ushort* Bb = d.Bt + (size_t)n0 * d.ldb + kb;
    const int wm = (w >> 1) * 64, wn = (w & 1) * 32;
    const int lr = lane >> 3, lc = lane & 7;
    const int ch = lc ^ lr;

    auto stage = [&](int buf, int k0) {
        #pragma unroll
        for (int q = 0; q < 4; ++q) {
            int seg = q * 4 + w;
            int row = seg * 8 + lr;
            gl_lds16(Ab + (size_t)row * d.lda + k0 + ch * 8,
                     (void*)(As[buf] + seg * 512));
        }
        #pragma unroll
        for (int q = 0; q < 2; ++q) {
            int seg = q * 4 + w;
            int row = seg * 8 + lr;
            gl_lds16(Bb + (size_t)row * d.ldb + k0 + ch * 8,
                     (void*)(Bs[buf] + seg * 512));
        }
    };

    f32x4 acc[4][2];
    #pragma unroll
    for (int i = 0; i < 4; ++i)
        #pragma unroll
        for (int j = 0; j < 2; ++j) acc[i][j] = (f32x4)0.f;

    auto compute = [&](int buf) {
        #pragma unroll
        for (int t2 = 0; t2 < 2; ++t2) {
            s16x8 af[4];
            #pragma unroll
            for (int i = 0; i < 4; ++i) {
                int r = wm + i * 16 + l16;
                int p = (t2 * 4 + quad) ^ (r & 7);
                af[i] = *(const s16x8*)(As[buf] + r * 64 + p * 8);
            }
            #pragma unroll
            for (int j = 0; j < 2; ++j) {
                int r = wn + j * 16 + l16;
                int p = (t2 * 4 + quad) ^ (r & 7);
                s16x8 bfr = *(const s16x8*)(Bs[buf] + r * 64 + p * 8);
                #pragma unroll
                for (int i = 0; i < 4; ++i)
                    acc[i][j] = __builtin_amdgcn_mfma_f32_16x16x32_bf16(af[i], bfr, acc[i][j], 0, 0, 0);
            }
        }
    };

    stage(0, 0);
    __syncthreads();
    int cur = 0;
    for (int t = 0; t < nk - 1; ++t) {
        stage(cur ^ 1, (t + 1) << 6);
        compute(cur);
        __syncthreads();
        cur ^= 1;
    }
    compute(cur);

    float* P = d.P + (size_t)slice * ((size_t)ROWS * 512);
    #pragma unroll
    for (int i = 0; i < 4; ++i) {
        #pragma unroll
        for (int j = 0; j < 2; ++j) {
            int col = n0 + wn + j * 16 + l16;
            #pragma unroll
            for (int r = 0; r < 4; ++r)
                P[(size_t)(m0 + wm + i * 16 + quad * 4 + r) * 512 + col] = acc[i][j][r];
        }
    }
}

/* ============ flash attention: O = softmax(Q K^T / 8, klen) V ===============
 * QBLK=32, 128-thread blocks (2 waves), grid (16,64) = 1024 blocks = 4
 * blocks/CU; independent blocks overlap softmax with MFMA (verified rd 13).
 * Masked QK skip; K0/V0 prefetch hoists; XCD swizzle.
 */
__global__ __launch_bounds__(128) void flash_attn(
    const ushort* __restrict__ Q, int ldq,
    const ushort* __restrict__ K, int ldk,
    const ushort* __restrict__ Vt,
    ushort* __restrict__ O, int ldo, int klen)
{
    __shared__ __attribute__((aligned(16))) ushort KVs[8192];
    __shared__ __attribute__((aligned(16))) ushort Es[2][2048];
    const int tid = threadIdx.x, w = tid >> 6, lane = tid & 63;
    const int l16 = lane & 15, quad = lane >> 4;
    int bqx = blockIdx.x, bhy = blockIdx.y;
    swz8(bqx, bhy, gridDim.x, gridDim.y);
    const int bh = bhy, b = bh >> 3, h = bh & 7;
    const int q0 = bqx * 32;

    const ushort* Qb = Q + (size_t)(b * SEQ) * ldq + h * D_HEAD;
    const ushort* Kb = K + (size_t)(b * SEQ) * ldk + h * D_HEAD;
    const ushort* Vb = Vt + (size_t)bh * (D_HEAD * SEQ);

    auto stageK = [&](int kc) {
        #pragma unroll
        for (int it = 0; it < 8; ++it) {
            int cc = (it * 2 + w) * 64 + lane;
            int row = cc >> 3;
            int dch = (cc & 7) ^ (row & 7);
            gl_lds16(Kb + (size_t)(kc * 128 + row) * ldk + dch * 8,
                     (void*)(KVs + (size_t)(it * 2 + w) * 512));
        }
    };
    auto stageV = [&](int kc) {
        #pragma unroll
        for (int it = 0; it < 8; ++it) {
            int cc = (it * 2 + w) * 64 + lane;
            int dd = cc >> 4;
            int kch = (cc & 15) ^ (dd & 15);
            gl_lds16(Vb + (size_t)dd * SEQ + kc * 128 + kch * 8,
                     (void*)(KVs + (size_t)(it * 2 + w) * 512));
        }
    };

    stageK(0);                           /* K0 latency hides under Q loads */

    s16x8 af0, af1;
    {
        const ushort* qr = Qb + (size_t)(q0 + w * 16 + l16) * ldq + quad * 8;
        af0 = *(const s16x8*)(qr);
        af1 = *(const s16x8*)(qr + 32);
    }

    f32x4 sc[32];

    #pragma unroll
    for (int kc = 0; kc < 4; ++kc) {
        if (kc > 0) stageK(kc);          /* after prev trailing barrier: safe */
        __syncthreads();                 /* K(kc) staged */
        #pragma unroll
        for (int kt = 0; kt < 8; ++kt) {
            if (kc * 128 + kt * 16 < klen) {   /* skip fully-masked key tiles */
                int r0 = kt * 16 + l16;
                s16x8 b0 = *(const s16x8*)(KVs + r0 * 64 + ((quad)     ^ (r0 & 7)) * 8);
                s16x8 b1 = *(const s16x8*)(KVs + r0 * 64 + ((4 + quad) ^ (r0 & 7)) * 8);
                f32x4 a = __builtin_amdgcn_mfma_f32_16x16x32_bf16(af0, b0, (f32x4)0.f, 0, 0, 0);
                sc[kc * 8 + kt] = __builtin_amdgcn_mfma_f32_16x16x32_bf16(af1, b1, a, 0, 0, 0);
            }
        }
        __syncthreads();                 /* all waves done reading KVs */
    }

    stageV(0);                           /* V0 latency hides under softmax */

    float inv[4];
    #pragma unroll
    for (int r = 0; r < 4; ++r) {
        float m = -1e30f;
        #pragma unroll
        for (int j = 0; j < 32; ++j) {
            bool valid = (j * 16 + l16) < klen;
            m = valid ? fmaxf(m, sc[j][r]) : m;
        }
        m = fmaxf(m, __shfl_xor(m, 1));
        m = fmaxf(m, __shfl_xor(m, 2));
        m = fmaxf(m, __shfl_xor(m, 4));
        m = fmaxf(m, __shfl_xor(m, 8));
        float ssum = 0.f;
        #pragma unroll
        for (int j = 0; j < 32; ++j) {
            bool valid = (j * 16 + l16) < klen;
            float e = valid ? __expf((sc[j][r] - m) * 0.125f) : 0.f;
            sc[j][r] = e;                /* unconditional: zeroes masked tiles */
            ssum += e;
        }
        ssum += __shfl_xor(ssum, 1);
        ssum += __shfl_xor(ssum, 2);
        ssum += __shfl_xor(ssum, 4);
        ssum += __shfl_xor(ssum, 8);
        inv[r] = 1.f / ssum;
    }

    f32x4 oacc[4];
    #pragma unroll
    for (int jd = 0; jd < 4; ++jd) oacc[jd] = (f32x4)0.f;
    #pragma unroll
    for (int kc = 0; kc < 4; ++kc) {
        if (kc > 0) stageV(kc);          /* after prev trailing barrier: safe */
        #pragma unroll
        for (int j = 0; j < 8; ++j) {
            int lcj = j * 2 + (l16 >> 3);
            #pragma unroll
            for (int r = 0; r < 4; ++r) {
                int m = quad * 4 + r;
                Es[w][m * 128 + (lcj ^ m) * 8 + (l16 & 7)] = f2bf(sc[kc * 8 + j][r]);
            }
        }
        __syncthreads();                 /* V(kc) staged (vmcnt drained) */
        #pragma unroll
        for (int ks = 0; ks < 4; ++ks) {
            int lc = ks * 4 + quad;
            s16x8 ea = *(const s16x8*)(&Es[w][l16 * 128 + (lc ^ l16) * 8]);
            #pragma unroll
            for (int jd = 0; jd < 4; ++jd) {
                int row = jd * 16 + l16;
                s16x8 vb = *(const s16x8*)(KVs + row * 128 + (lc ^ l16) * 8);
                oacc[jd] = __builtin_amdgcn_mfma_f32_16x16x32_bf16(ea, vb, oacc[jd], 0, 0, 0);
            }
        }
        __syncthreads();                 /* all waves done reading KVs/Es */
    }

    ushort* Ob = O + (size_t)(b * SEQ) * ldo + h * D_HEAD;
    #pragma unroll
    for (int jd = 0; jd < 4; ++jd)
        #pragma unroll
        for (int r = 0; r < 4; ++r)
            Ob[(size_t)(q0 + w * 16 + quad * 4 + r) * ldo + jd * 16 + l16] =
                f2bf(oacc[jd][r] * inv[r]);
}

/* ============ merged prologue: weight repack (32x32, verified rd 13) ========
 * + input projection folded in as extra flat-grid blocks (independent work;
 * proj rides in the repack's scheduling shadow, one launch gap removed).
 */
struct AttnPtrs { const float* p[48]; };
struct FfPtrs   { const float* p[16]; };
struct ProjArgs {
    const float *x0, *w0, *b0, *p0; float* o0; ushort* ob0;
    const float *x1, *w1, *b1, *p1; float* o1; ushort* ob1;
};

__global__ __launch_bounds__(256) void repack_all(
    AttnPtrs A, FfPtrs F, ushort* __restrict__ wa, ushort* __restrict__ wf,
    ProjArgs PJ)
{
    __shared__ float t[32][33];
    const int tx = threadIdx.x & 31, ty = threadIdx.x >> 5;
    const int id = blockIdx.x;
    if (id < 12288) {                    /* attn: 48 mats x 256 tiles */
        int z = id >> 8, tt = id & 255;
        int n0 = (tt & 15) * 32, k0 = (tt >> 4) * 32;
        const float* in = A.p[z];
        ushort* o = wa + (size_t)z * 262144;
        #pragma unroll
        for (int r = 0; r < 4; ++r)
            t[ty + r * 8][tx] = in[(size_t)(k0 + ty + r * 8) * 512 + n0 + tx];
        __syncthreads();
        #pragma unroll
        for (int r = 0; r < 4; ++r)
            o[(size_t)(n0 + ty + r * 8) * 512 + k0 + tx] = f2bf(t[tx][ty + r * 8]);
    } else if (id < 28672) {             /* ff: 16 mats x 1024 tiles */
        int id2 = id - 12288;
        int z = id2 >> 10, tt = id2 & 1023;
        int Kd = (z < 8) ? 512 : 2048, Nd = (z < 8) ? 2048 : 512;
        const float* in = F.p[z];
        ushort* o = wf + (size_t)z * (512 * 2048);
        int tn = Nd / 32;
        int n0 = (tt % tn) * 32, k0 = (tt / tn) * 32;
        #pragma unroll
        for (int r = 0; r < 4; ++r)
            t[ty + r * 8][tx] = in[(size_t)(k0 + ty + r * 8) * Nd + n0 + tx];
        __syncthreads();
        #pragma unroll
        for (int r = 0; r < 4; ++r)
            o[(size_t)(n0 + ty + r * 8) * Kd + k0 + tx] = f2bf(t[tx][ty + r * 8]);
    } else {                             /* input projection: 16384 blocks */
        int idx = (id - 28672) * 256 + threadIdx.x;   /* 0 .. 2*ROWS*512-1 */
        int z = idx >> 21;                            /* ROWS*512 = 2^21 */
        int e = idx & ((1 << 21) - 1);
        const float* x = z ? PJ.x1 : PJ.x0;
        const float* w = z ? PJ.w1 : PJ.w0;
        const float* bias = z ? PJ.b1 : PJ.b0;
        const float* pos = z ? PJ.p1 : PJ.p0;
        float* out32 = z ? PJ.o1 : PJ.o0;
        ushort* outb = z ? PJ.ob1 : PJ.ob0;
        int in_size = z ? 8 : 16;
        int col = e & (D_MODEL - 1);
        int row = e >> 9;
        int l   = row & (SEQ - 1);
        const float* xr = x + (size_t)row * in_size;
        float acc = bias[col] + pos[(size_t)l * D_MODEL + col];
        for (int tI = 0; tI < in_size; ++tI) acc += xr[tI] * w[(size_t)tI * D_MODEL + col];
        out32[e] = acc;
        outb[e]  = f2bf(acc);
    }
}

/* ============ split-K reduce + opt gemm-bias + residual + LayerNorm ========
 * one 64-lane wave per 512-col row. p = f32 partials [2][ROWS*512].
 */
__global__ __launch_bounds__(256) void add_ln2(
    const float* __restrict__ p, const float* __restrict__ gb,
    const float* __restrict__ x,
    const float* __restrict__ g, const float* __restrict__ b,
    float* __restrict__ out32, ushort* __restrict__ outb)
{
    const int row  = blockIdx.x * 4 + (threadIdx.x >> 6);
    const int lane = threadIdx.x & 63;
    const int c0   = lane * 8;
    const size_t base = (size_t)row * D_MODEL + c0;
    const float* p1 = p + (size_t)ROWS * 512;
    f32x4 a0 = *(const f32x4*)(p + base),  a1 = *(const f32x4*)(p + base + 4);
    f32x4 c0v= *(const f32x4*)(p1 + base), c1v= *(const f32x4*)(p1 + base + 4);
    f32x4 x0 = *(const f32x4*)(x + base),  x1 = *(const f32x4*)(x + base + 4);
    float v[8];
    #pragma unroll
    for (int j = 0; j < 4; ++j) {
        v[j]     = a0[j] + c0v[j] + x0[j];
        v[4 + j] = a1[j] + c1v[j] + x1[j];
    }
    if (gb) {
        f32x4 gb0 = *(const f32x4*)(gb + c0), gb1 = *(const f32x4*)(gb + c0 + 4);
        #pragma unroll
        for (int j = 0; j < 4; ++j) { v[j] += gb0[j]; v[4 + j] += gb1[j]; }
    }
    float s = 0.f;
    #pragma unroll
    for (int j = 0; j < 8; ++j) s += v[j];
    #pragma unroll
    for (int off = 32; off; off >>= 1) s += __shfl_xor(s, off);
    float mu = s * (1.f / D_MODEL);
    float q = 0.f;
    #pragma unroll
    for (int j = 0; j < 8; ++j) { v[j] -= mu; q += v[j] * v[j]; }
    #pragma unroll
    for (int off = 32; off; off >>= 1) q += __shfl_xor(q, off);
    float rs = rsqrtf(q * (1.f / D_MODEL) + LN_EPS);
    f32x4 g0 = *(const f32x4*)(g + c0), g1 = *(const f32x4*)(g + c0 + 4);
    f32x4 b0 = *(const f32x4*)(b + c0), b1 = *(const f32x4*)(b + c0 + 4);
    f32x4 y0, y1;
    union { ushort u[8]; s16x8 w; } pk;
    #pragma unroll
    for (int j = 0; j < 4; ++j) {
        y0[j] = v[j]     * rs * g0[j] + b0[j];
        y1[j] = v[4 + j] * rs * g1[j] + b1[j];
        pk.u[j]     = f2bf(y0[j]);
        pk.u[4 + j] = f2bf(y1[j]);
    }
    *(f32x4*)(out32 + base)     = y0;
    *(f32x4*)(out32 + base + 4) = y1;
    *(s16x8*)(outb + base)      = pk.w;
}

/* ============ final projection: one wave per row, contiguous W reads ======= */
__global__ __launch_bounds__(256) void final_proj(
    const float* __restrict__ X, const float* __restrict__ W,
    const float* __restrict__ b, float* __restrict__ out)
{
    const int row  = blockIdx.x * 4 + (threadIdx.x >> 6);
    const int lane = threadIdx.x & 63;
    const float* xr = X + (size_t)row * D_MODEL + lane * 8;
    f32x4 x0 = *(const f32x4*)(xr), x1 = *(const f32x4*)(xr + 4);
    const float* wr = W + (size_t)lane * 64;      /* rows lane*8..lane*8+7, 8 cols */
    f32x4 pa = (f32x4)0.f, pb = (f32x4)0.f;
    #pragma unroll
    for (int j = 0; j < 8; ++j) {
        float xv = (j < 4) ? x0[j] : x1[j - 4];
        f32x4 w0 = *(const f32x4*)(wr + j * 8);
        f32x4 w1 = *(const f32x4*)(wr + j * 8 + 4);
        #pragma unroll
        for (int c = 0; c < 4; ++c) { pa[c] += xv * w0[c]; pb[c] += xv * w1[c]; }
    }
    #pragma unroll
    for (int off = 32; off; off >>= 1) {
        #pragma unroll
        for (int c = 0; c < 4; ++c) {
            pa[c] += __shfl_xor(pa[c], off);
            pb[c] += __shfl_xor(pb[c], off);
        }
    }
    if (lane == 0) {
        float* o = out + (size_t)row * 8;
        #pragma unroll
        for (int c = 0; c < 4; ++c) { o[c] = pa[c] + b[c]; o[4 + c] = pb[c] + b[4 + c]; }
    }
}

/* ============================ host orchestration ============================ */
extern "C" void kernel_launch(void* const* d_in, const int* in_sizes, int n_in,
                              void* d_out, int out_size, void* d_ws, size_t ws_size,
                              hipStream_t stream)
{
    const float* src         = (const float*)d_in[0];
    const float* tgt         = (const float*)d_in[1];
    const float* src_pos     = (const float*)d_in[2];
    const float* tgt_pos     = (const float*)d_in[3];
    const float* src_lin_w   = (const float*)d_in[4];
    const float* src_lin_b   = (const float*)d_in[5];
    const float* tgt_lin_w   = (const float*)d_in[6];
    const float* tgt_lin_b   = (const float*)d_in[7];
    const float* enc_wq      = (const float*)d_in[8];
    const float* enc_wk      = (const float*)d_in[9];
    const float* enc_wv      = (const float*)d_in[10];
    const float* enc_wo      = (const float*)d_in[11];
    const float* enc_ff1_w   = (const float*)d_in[12];
    const float* enc_ff1_b   = (const float*)d_in[13];
    const float* enc_ff2_w   = (const float*)d_in[14];
    const float* enc_ff2_b   = (const float*)d_in[15];
    const float* enc_ln1_g   = (const float*)d_in[16];
    const float* enc_ln1_b   = (const float*)d_in[17];
    const float* enc_ln2_g   = (const float*)d_in[18];
    const float* enc_ln2_b   = (const float*)d_in[19];
    const float* dec_sa_wq   = (const float*)d_in[20];
    const float* dec_sa_wk   = (const float*)d_in[21];
    const float* dec_sa_wv   = (const float*)d_in[22];
    const float* dec_sa_wo   = (const float*)d_in[23];
    const float* dec_ca_wq   = (const float*)d_in[24];
    const float* dec_ca_wk   = (const float*)d_in[25];
    const float* dec_ca_wv   = (const float*)d_in[26];
    const float* dec_ca_wo   = (const float*)d_in[27];
    const float* dec_ff1_w   = (const float*)d_in[28];
    const float* dec_ff1_b   = (const float*)d_in[29];
    const float* dec_ff2_w   = (const float*)d_in[30];
    const float* dec_ff2_b   = (const float*)d_in[31];
    const float* dec_ln1_g   = (const float*)d_in[32];
    const float* dec_ln1_b   = (const float*)d_in[33];
    const float* dec_ln2_g   = (const float*)d_in[34];
    const float* dec_ln2_b   = (const float*)d_in[35];
    const float* dec_ln3_g   = (const float*)d_in[36];
    const float* dec_ln3_b   = (const float*)d_in[37];
    const float* proj_w      = (const float*)d_in[38];
    const float* proj_b      = (const float*)d_in[39];

    /* ---- workspace carve ---- */
    char* p = (char*)d_ws;
    auto carve = [&](size_t bytes) { char* r = p; p += (bytes + 255) & ~(size_t)255; return r; };
    ushort* enc_xb = (ushort*)carve((size_t)ROWS * D_MODEL * 2);
    ushort* dec_xb = (ushort*)carve((size_t)ROWS * D_MODEL * 2);
    float*  enc_x32= (float*) carve((size_t)ROWS * D_MODEL * 4);
    float*  dec_x32= (float*) carve((size_t)ROWS * D_MODEL * 4);
    ushort* qkvb   = (ushort*)carve((size_t)ROWS * 1536 * 2);
    ushort* qb     = (ushort*)carve((size_t)ROWS * D_MODEL * 2);
    ushort* kvb    = (ushort*)carve((size_t)ROWS * 1024 * 2);
    ushort* ctxb   = (ushort*)carve((size_t)ROWS * D_MODEL * 2);
    float*  pf     = (float*) carve((size_t)2 * ROWS * D_MODEL * 4);
    ushort* ffhb   = (ushort*)carve((size_t)ROWS * D_FF * 2);
    ushort* vt     = (ushort*)carve((size_t)64 * D_HEAD * SEQ * 2);
    ushort* wa     = (ushort*)carve((size_t)48 * 262144 * 2);
    ushort* wf     = (ushort*)carve((size_t)16 * 1048576 * 2);

    const dim3 blk(256);

    /* ---- prologue: weight repack + input projection (1 merged launch) ---- */
    {
        AttnPtrs A;
        for (int i = 0; i < 4; ++i) {
            const size_t o = (size_t)i * 262144;
            A.p[i * 3 + 0] = enc_wq + o;  A.p[i * 3 + 1] = enc_wk + o;  A.p[i * 3 + 2] = enc_wv + o;
            A.p[12 + i] = enc_wo + o;
            A.p[16 + i * 3 + 0] = dec_sa_wq + o; A.p[16 + i * 3 + 1] = dec_sa_wk + o;
            A.p[16 + i * 3 + 2] = dec_sa_wv + o;
            A.p[28 + i] = dec_sa_wo + o;
            A.p[32 + i * 2 + 0] = dec_ca_wk + o; A.p[32 + i * 2 + 1] = dec_ca_wv + o;
            A.p[40 + i] = dec_ca_wq + o;
            A.p[44 + i] = dec_ca_wo + o;
        }
        FfPtrs F;
        for (int i = 0; i < 4; ++i) {
            F.p[0 + i]  = enc_ff1_w + (size_t)i * 1048576;
            F.p[4 + i]  = dec_ff1_w + (size_t)i * 1048576;
            F.p[8 + i]  = enc_ff2_w + (size_t)i * 1048576;
            F.p[12 + i] = dec_ff2_w + (size_t)i * 1048576;
        }
        ProjArgs PJ;
        PJ.x0 = src; PJ.w0 = src_lin_w; PJ.b0 = src_lin_b; PJ.p0 = src_pos;
        PJ.o0 = enc_x32; PJ.ob0 = enc_xb;
        PJ.x1 = tgt; PJ.w1 = tgt_lin_w; PJ.b1 = tgt_lin_b; PJ.p1 = tgt_pos;
        PJ.o1 = dec_x32; PJ.ob1 = dec_xb;
        repack_all<<<dim3(28672 + 16384), blk, 0, stream>>>(A, F, wa, wf, PJ);
    }

    auto mkd = [&](const ushort* A, int lda, const ushort* Bt, int ldb,
                   ushort* C, int ldc, int N, int K,
                   const float* bias, int relu, ushort* VT, int vcol0) {
        GDesc d; d.A = A; d.lda = lda; d.Bt = Bt; d.ldb = ldb;
        d.C = C; d.ldc = ldc; d.N = N; d.K = K;
        d.bias = bias; d.relu = relu; d.VT = VT; d.vcol0 = vcol0;
        return d;
    };
    auto g64 = [&](const GDesc& d) {
        gemm_one<<<dim3(d.N / 64, ROWS / 128), blk, 0, stream>>>(d);
    };
    auto gsk = [&](const ushort* A, int lda, const ushort* Bt, int K) {
        SKDesc d; d.A = A; d.lda = lda; d.Bt = Bt; d.ldb = K; d.P = pf; d.K = K;
        gemm_sk<<<dim3(8, ROWS / 128, 2), blk, 0, stream>>>(d);
    };

    /* ===================== encoder ===================== */
    for (int i = 0; i < 4; ++i) {
        g64(mkd(enc_xb, 512, wa + (size_t)(i * 3) * 262144, 512, qkvb, 1536,
                1536, 512, nullptr, 0, vt, 1024));
        flash_attn<<<dim3(16, 64), dim3(128), 0, stream>>>(qkvb, 1536, qkvb + 512, 1536, vt,
                                                           ctxb, D_MODEL, SEQ);
        gsk(ctxb, 512, wa + (size_t)(12 + i) * 262144, 512);
        add_ln2<<<ROWS / 4, blk, 0, stream>>>(pf, nullptr, enc_x32,
                                              enc_ln1_g + i * 512, enc_ln1_b + i * 512,
                                              enc_x32, enc_xb);
        g64(mkd(enc_xb, 512, wf + (size_t)i * 1048576, 512, ffhb, 2048,
                2048, 512, enc_ff1_b + i * 2048, 1, nullptr, 0));
        gsk(ffhb, 2048, wf + (size_t)(8 + i) * 1048576, 2048);
        add_ln2<<<ROWS / 4, blk, 0, stream>>>(pf, enc_ff2_b + i * 512, enc_x32,
                                              enc_ln2_g + i * 512, enc_ln2_b + i * 512,
                                              enc_x32, enc_xb);
    }

    /* ===================== decoder ===================== */
    for (int i = 0; i < 4; ++i) {
        /* masked self-attention */
        g64(mkd(dec_xb, 512, wa + (size_t)(16 + i * 3) * 262144, 512, qkvb, 1536,
                1536, 512, nullptr, 0, vt, 1024));
        flash_attn<<<dim3(16, 64), dim3(128), 0, stream>>>(qkvb, 1536, qkvb + 512, 1536, vt,
                                                           ctxb, D_MODEL, KLEN_MASKED);
        gsk(ctxb, 512, wa + (size_t)(28 + i) * 262144, 512);
        add_ln2<<<ROWS / 4, blk, 0, stream>>>(pf, nullptr, dec_x32,
                                              dec_ln1_g + i * 512, dec_ln1_b + i * 512,
                                              dec_x32, dec_xb);
        /* cross-attention: q-proj (dec_x) and kv-proj (enc_x) in ONE launch */
        {
            GDesc dq = mkd(dec_xb, 512, wa + (size_t)(40 + i) * 262144, 512, qb, 512,
                           512, 512, nullptr, 0, nullptr, 0);
            GDesc dkv = mkd(enc_xb, 512, wa + (size_t)(32 + i * 2) * 262144, 512, kvb, 1024,
                            1024, 512, nullptr, 0, vt, 512);
            gemm_two<<<dim3(16, ROWS / 128, 2), blk, 0, stream>>>(dq, dkv);
        }
        flash_attn<<<dim3(16, 64), dim3(128), 0, stream>>>(qb, 512, kvb, 1024, vt,
                                                           ctxb, D_MODEL, SEQ);
        gsk(ctxb, 512, wa + (size_t)(44 + i) * 262144, 512);
        add_ln2<<<ROWS / 4, blk, 0, stream>>>(pf, nullptr, dec_x32,
                                              dec_ln2_g + i * 512, dec_ln2_b + i * 512,
                                              dec_x32, dec_xb);
        /* feed-forward */
        g64(mkd(dec_xb, 512, wf + (size_t)(4 + i) * 1048576, 512, ffhb, 2048,
                2048, 512, dec_ff1_b + i * 2048, 1, nullptr, 0));
        gsk(ffhb, 2048, wf + (size_t)(12 + i) * 1048576, 2048);
        add_ln2<<<ROWS / 4, blk, 0, stream>>>(pf, dec_ff2_b + i * 512, dec_x32,
                                              dec_ln3_g + i * 512, dec_ln3_b + i * 512,
                                              dec_x32, dec_xb);
    }

    /* final projection */
    final_proj<<<ROWS / 4, blk, 0, stream>>>(dec_x32, proj_w, proj_b, (float*)d_out);
}